// Round 1
// baseline (637.867 us; speedup 1.0000x reference)
//
#include <hip/hip_runtime.h>

// Problem constants
#define MTOT (16 * 4096)   // 65536 queries
#define KDIM 256           // vector dim
#define CBSZ 1024          // codebook size

// GEMM tiling
#define BM 128
#define BN 128
#define BK 8
#define LDSS (BM + 4)      // padded LDS stride (132 floats)

// ---------------------------------------------------------------------------
// Kernel 1: codebook squared norms h[c] = sum(c^2); also zero the loss accum.
// One wave (64 lanes) per codeword; lane loads float4 (4*64 = 256 elems).
// ---------------------------------------------------------------------------
__global__ void vq_norms(const float* __restrict__ cb, float* __restrict__ h,
                         float* __restrict__ loss_sum) {
    int wave = threadIdx.x >> 6;
    int lane = threadIdx.x & 63;
    int cw = blockIdx.x * 4 + wave;   // grid 256 blocks * 4 waves = 1024
    float4 v = *(reinterpret_cast<const float4*>(cb + (size_t)cw * KDIM) + lane);
    float s = v.x * v.x + v.y * v.y + v.z * v.z + v.w * v.w;
    #pragma unroll
    for (int d = 32; d; d >>= 1) s += __shfl_xor(s, d);
    if (lane == 0) h[cw] = s;
    if (blockIdx.x == 0 && threadIdx.x == 0) *loss_sum = 0.0f;
}

// ---------------------------------------------------------------------------
// Kernel 2: fused GEMM + row argmin.
// Each block: BM=128 queries, loops over 8 chunks of BN=128 codewords.
// Surrogate distance s = h[c] - 2 * dot(x, c)  (argmin-equivalent).
// ---------------------------------------------------------------------------
__global__ __launch_bounds__(256, 2)
void vq_main(const float* __restrict__ A,   // z_e flat [MTOT][KDIM]
             const float* __restrict__ Bc,  // codebook [CBSZ][KDIM]
             const float* __restrict__ h,   // codebook norms [CBSZ]
             float* __restrict__ out_idx_f, // d_out + MTOT*KDIM
             int* __restrict__ out_idx_i)   // ws ints
{
    __shared__ float As[2][BK][LDSS];
    __shared__ float Bs[2][BK][LDSS];

    const int tid = threadIdx.x;
    const int tx = tid & 15;          // column-thread 0..15
    const int ty = tid >> 4;          // row-thread 0..15
    const int rbase = blockIdx.x * BM;

    // staging assignment: 2 threads per row, each loads float4 (4 k's)
    const int ldRow = tid >> 1;            // 0..127
    const int ldSeg = (tid & 1) * 4;       // 0 or 4
    const float* aPtr = A + (size_t)(rbase + ldRow) * KDIM + ldSeg;

    float minv[8];
    int   mini[8];
    #pragma unroll
    for (int i = 0; i < 8; ++i) { minv[i] = 3.4e38f; mini[i] = 0; }

    for (int chunk = 0; chunk < 8; ++chunk) {
        const int cbase = chunk * BN;
        const float* bPtr = Bc + (size_t)(cbase + ldRow) * KDIM + ldSeg;

        float acc[8][8];
        #pragma unroll
        for (int i = 0; i < 8; ++i) {
            #pragma unroll
            for (int j = 0; j < 8; ++j) acc[i][j] = 0.0f;
        }

        float4 ar = *reinterpret_cast<const float4*>(aPtr);
        float4 br = *reinterpret_cast<const float4*>(bPtr);

        int buf = 0;
        for (int s = 0; s < KDIM / BK; ++s) {
            // write staged regs to LDS (transposed: [k][row])
            As[buf][ldSeg + 0][ldRow] = ar.x;
            As[buf][ldSeg + 1][ldRow] = ar.y;
            As[buf][ldSeg + 2][ldRow] = ar.z;
            As[buf][ldSeg + 3][ldRow] = ar.w;
            Bs[buf][ldSeg + 0][ldRow] = br.x;
            Bs[buf][ldSeg + 1][ldRow] = br.y;
            Bs[buf][ldSeg + 2][ldRow] = br.z;
            Bs[buf][ldSeg + 3][ldRow] = br.w;
            __syncthreads();

            if (s < KDIM / BK - 1) {   // prefetch next k-slice
                ar = *reinterpret_cast<const float4*>(aPtr + (s + 1) * BK);
                br = *reinterpret_cast<const float4*>(bPtr + (s + 1) * BK);
            }

            #pragma unroll
            for (int kk = 0; kk < BK; ++kk) {
                float4 a0 = *reinterpret_cast<const float4*>(&As[buf][kk][ty * 4]);
                float4 a1 = *reinterpret_cast<const float4*>(&As[buf][kk][64 + ty * 4]);
                float4 b0 = *reinterpret_cast<const float4*>(&Bs[buf][kk][tx * 4]);
                float4 b1 = *reinterpret_cast<const float4*>(&Bs[buf][kk][64 + tx * 4]);
                float a[8] = {a0.x, a0.y, a0.z, a0.w, a1.x, a1.y, a1.z, a1.w};
                float b[8] = {b0.x, b0.y, b0.z, b0.w, b1.x, b1.y, b1.z, b1.w};
                #pragma unroll
                for (int i = 0; i < 8; ++i) {
                    #pragma unroll
                    for (int j = 0; j < 8; ++j)
                        acc[i][j] = fmaf(a[i], b[j], acc[i][j]);
                }
            }
            buf ^= 1;
        }

        // epilogue: surrogate distance + running argmin (ascending col order)
        #pragma unroll
        for (int j = 0; j < 8; ++j) {
            const int col = cbase + ((j < 4) ? (tx * 4 + j) : (64 + tx * 4 + (j - 4)));
            const float hc = h[col];
            #pragma unroll
            for (int i = 0; i < 8; ++i) {
                float s = fmaf(-2.0f, acc[i][j], hc);
                if (s < minv[i]) { minv[i] = s; mini[i] = col; }
            }
        }
        __syncthreads();  // keep LDS buffers safe across chunk boundary
    }

    // reduce (min, idx) across the 16 column-threads (same ty group, lanes
    // differ only in low 4 bits -> stays inside the wave)
    #pragma unroll
    for (int i = 0; i < 8; ++i) {
        float v = minv[i];
        int ix = mini[i];
        #pragma unroll
        for (int d = 1; d < 16; d <<= 1) {
            float ov = __shfl_xor(v, d);
            int oi = __shfl_xor(ix, d);
            if (ov < v || (ov == v && oi < ix)) { v = ov; ix = oi; }
        }
        if (tx == 0) {
            const int row = rbase + ((i < 4) ? (ty * 4 + i) : (64 + ty * 4 + (i - 4)));
            out_idx_f[row] = (float)ix;
            out_idx_i[row] = ix;
        }
    }
}

// ---------------------------------------------------------------------------
// Kernel 3: gather z_q = codebook[idx] and accumulate commitment-loss sum.
// One wave per query (4 queries per block).
// ---------------------------------------------------------------------------
__global__ void vq_gather(const float* __restrict__ A, const float* __restrict__ Bc,
                          const int* __restrict__ idx, float* __restrict__ zq,
                          float* __restrict__ loss_sum) {
    int wave = threadIdx.x >> 6;
    int lane = threadIdx.x & 63;
    int q = blockIdx.x * 4 + wave;
    int c = idx[q];
    float4 cv = *reinterpret_cast<const float4*>(Bc + (size_t)c * KDIM + lane * 4);
    float4 zv = *reinterpret_cast<const float4*>(A + (size_t)q * KDIM + lane * 4);
    *reinterpret_cast<float4*>(zq + (size_t)q * KDIM + lane * 4) = cv;
    float dx = cv.x - zv.x, dy = cv.y - zv.y, dz = cv.z - zv.z, dw = cv.w - zv.w;
    float s = dx * dx + dy * dy + dz * dz + dw * dw;
    #pragma unroll
    for (int d = 32; d; d >>= 1) s += __shfl_xor(s, d);
    __shared__ float ps[4];
    if (lane == 0) ps[wave] = s;
    __syncthreads();
    if (threadIdx.x == 0)
        atomicAdd(loss_sum, ps[0] + ps[1] + ps[2] + ps[3]);
}

// ---------------------------------------------------------------------------
// Kernel 4: finalize loss = sum / (B*N*D)
// ---------------------------------------------------------------------------
__global__ void vq_finish(const float* __restrict__ loss_sum, float* __restrict__ out_loss) {
    *out_loss = *loss_sum * (1.0f / 16777216.0f);
}

extern "C" void kernel_launch(void* const* d_in, const int* in_sizes, int n_in,
                              void* d_out, int out_size, void* d_ws, size_t ws_size,
                              hipStream_t stream) {
    const float* z_e = (const float*)d_in[0];   // [16,4096,256] fp32
    const float* cb  = (const float*)d_in[1];   // [1024,256] fp32

    float* out   = (float*)d_out;
    float* zq    = out;                                  // MTOT*KDIM floats
    float* oidx  = out + (size_t)MTOT * KDIM;            // MTOT floats
    float* oloss = out + (size_t)MTOT * KDIM + MTOT;     // 1 float

    float* h    = (float*)d_ws;                          // 1024 floats
    int*   iidx = (int*)((float*)d_ws + CBSZ);           // MTOT ints
    float* lsum = (float*)d_ws + CBSZ + MTOT;            // 1 float

    vq_norms<<<CBSZ / 4, 256, 0, stream>>>(cb, h, lsum);
    vq_main<<<MTOT / BM, 256, 0, stream>>>(z_e, cb, h, oidx, iidx);
    vq_gather<<<MTOT / 4, 256, 0, stream>>>(z_e, cb, iidx, zq, lsum);
    vq_finish<<<1, 1, 0, stream>>>(lsum, oloss);
}

// Round 2
// 270.997 us; speedup vs baseline: 2.3538x; 2.3538x over previous
//
#include <hip/hip_runtime.h>

#define MTOT (16 * 4096)   // 65536 queries
#define KDIM 256           // vector dim
#define CBSZ 1024          // codebook size

using half4  = _Float16 __attribute__((ext_vector_type(4)));
using half8  = _Float16 __attribute__((ext_vector_type(8)));
using f32x16 = float    __attribute__((ext_vector_type(16)));

// ---------------------------------------------------------------------------
// Kernel 1 (prep): codebook -> fp16 hi/lo split + squared norms.
// One wave per codeword; lane handles 4 consecutive k's.
// ---------------------------------------------------------------------------
__global__ void vq_prep(const float* __restrict__ cb,
                        _Float16* __restrict__ cbh, _Float16* __restrict__ cbl,
                        float* __restrict__ hn) {
    const int wave = threadIdx.x >> 6;
    const int lane = threadIdx.x & 63;
    const int c = blockIdx.x * 4 + wave;            // 256 blocks * 4 = 1024
    float4 v = *(reinterpret_cast<const float4*>(cb + (size_t)c * KDIM) + lane);
    half4 hv, lv;
    hv.x = (_Float16)v.x; lv.x = (_Float16)(v.x - (float)hv.x);
    hv.y = (_Float16)v.y; lv.y = (_Float16)(v.y - (float)hv.y);
    hv.z = (_Float16)v.z; lv.z = (_Float16)(v.z - (float)hv.z);
    hv.w = (_Float16)v.w; lv.w = (_Float16)(v.w - (float)hv.w);
    *reinterpret_cast<half4*>(cbh + (size_t)c * KDIM + lane * 4) = hv;
    *reinterpret_cast<half4*>(cbl + (size_t)c * KDIM + lane * 4) = lv;
    float s = v.x * v.x + v.y * v.y + v.z * v.z + v.w * v.w;
    #pragma unroll
    for (int d = 32; d; d >>= 1) s += __shfl_xor(s, d);
    if (lane == 0) hn[c] = s;
}

// ---------------------------------------------------------------------------
// Kernel 2: MFMA distance GEMM + lane-local argmin.
// D[codeword][query] via mfma_f32_32x32x16_f16, fp16x3 split.
// Each wave: 32 queries, scans all 1024 codewords (2 chunks of 32 in flight).
// ---------------------------------------------------------------------------
__global__ __launch_bounds__(256, 2)
void vq_main(const float* __restrict__ A,          // z_e [MTOT][KDIM] fp32
             const _Float16* __restrict__ cbh,     // [CBSZ][KDIM]
             const _Float16* __restrict__ cbl,
             const float* __restrict__ hn,         // [CBSZ]
             float* __restrict__ out_idx_f,
             int* __restrict__ out_idx_i) {
    __shared__ float hs[CBSZ];
    const int tid = threadIdx.x;
    for (int i = tid; i < CBSZ; i += 256) hs[i] = hn[i];

    const int lane = tid & 63;
    const int wave = tid >> 6;
    const int m31 = lane & 31;       // query col (B) / codeword row (A)
    const int g = lane >> 5;         // k-group 0/1
    const int q = blockIdx.x * 128 + wave * 32 + m31;

    // Load this lane's query fragments for all 16 k-chunks, split hi/lo.
    half8 qh[16], ql[16];
    const float* ap = A + (size_t)q * KDIM + g * 8;
    #pragma unroll
    for (int c = 0; c < 16; ++c) {
        float4 f0 = *reinterpret_cast<const float4*>(ap + c * 16);
        float4 f1 = *reinterpret_cast<const float4*>(ap + c * 16 + 4);
        float fv[8] = {f0.x, f0.y, f0.z, f0.w, f1.x, f1.y, f1.z, f1.w};
        half8 h, l;
        #pragma unroll
        for (int j = 0; j < 8; ++j) {
            h[j] = (_Float16)fv[j];
            l[j] = (_Float16)(fv[j] - (float)h[j]);
        }
        qh[c] = h; ql[c] = l;
    }
    __syncthreads();   // hs ready

    float minv = 3.4e38f;
    int mini = 0;

    for (int cc = 0; cc < 32; cc += 2) {
        const int cbase = cc * 32;
        const _Float16* ah0 = cbh + (size_t)(cbase + m31) * KDIM + g * 8;
        const _Float16* al0 = cbl + (size_t)(cbase + m31) * KDIM + g * 8;
        const _Float16* ah1 = ah0 + 32 * KDIM;
        const _Float16* al1 = al0 + 32 * KDIM;

        f32x16 acc0 = {};
        f32x16 acc1 = {};
        #pragma unroll
        for (int c = 0; c < 16; ++c) {
            half8 Ah0 = *reinterpret_cast<const half8*>(ah0 + c * 16);
            half8 Al0 = *reinterpret_cast<const half8*>(al0 + c * 16);
            half8 Ah1 = *reinterpret_cast<const half8*>(ah1 + c * 16);
            half8 Al1 = *reinterpret_cast<const half8*>(al1 + c * 16);
            acc0 = __builtin_amdgcn_mfma_f32_32x32x16_f16(Ah0, qh[c], acc0, 0, 0, 0);
            acc1 = __builtin_amdgcn_mfma_f32_32x32x16_f16(Ah1, qh[c], acc1, 0, 0, 0);
            acc0 = __builtin_amdgcn_mfma_f32_32x32x16_f16(Al0, qh[c], acc0, 0, 0, 0);
            acc1 = __builtin_amdgcn_mfma_f32_32x32x16_f16(Al1, qh[c], acc1, 0, 0, 0);
            acc0 = __builtin_amdgcn_mfma_f32_32x32x16_f16(Ah0, ql[c], acc0, 0, 0, 0);
            acc1 = __builtin_amdgcn_mfma_f32_32x32x16_f16(Ah1, ql[c], acc1, 0, 0, 0);
        }

        // surrogate distance s = ||c||^2 - 2 x.c ; running argmin (ascending)
        #pragma unroll
        for (int r = 0; r < 16; ++r) {
            const int row = (r & 3) + 8 * (r >> 2) + 4 * g;
            const int cw = cbase + row;
            float s = fmaf(-2.0f, acc0[r], hs[cw]);
            if (s < minv) { minv = s; mini = cw; }
        }
        #pragma unroll
        for (int r = 0; r < 16; ++r) {
            const int row = (r & 3) + 8 * (r >> 2) + 4 * g;
            const int cw = cbase + 32 + row;
            float s = fmaf(-2.0f, acc1[r], hs[cw]);
            if (s < minv) { minv = s; mini = cw; }
        }
    }

    // combine the two half-wave row sets (tie -> lower index = np semantics)
    float ov = __shfl_xor(minv, 32);
    int oi = __shfl_xor(mini, 32);
    if (ov < minv || (ov == minv && oi < mini)) { minv = ov; mini = oi; }
    if (g == 0) {
        out_idx_f[q] = (float)mini;
        out_idx_i[q] = mini;
    }
}

// ---------------------------------------------------------------------------
// Kernel 3: gather z_q = codebook[idx], per-block loss partials (no atomics).
// One wave covers exactly one query row (64 float4) per iteration.
// ---------------------------------------------------------------------------
#define GATHER_BLOCKS 2048
__global__ void vq_gather(const float* __restrict__ A, const float* __restrict__ cb,
                          const int* __restrict__ idx, float* __restrict__ zq,
                          float* __restrict__ partial) {
    const float4* A4  = reinterpret_cast<const float4*>(A);
    const float4* cb4 = reinterpret_cast<const float4*>(cb);
    float4* zq4 = reinterpret_cast<float4*>(zq);

    const int tg = blockIdx.x * 256 + threadIdx.x;   // 524288 threads
    float acc = 0.0f;
    #pragma unroll
    for (int it = 0; it < 8; ++it) {
        const size_t gi = (size_t)tg + (size_t)it * (GATHER_BLOCKS * 256);
        const int qq = (int)(gi >> 6);
        const int seg = (int)(gi & 63);
        const int c = idx[qq];                       // wave-uniform
        float4 cv = cb4[(size_t)c * 64 + seg];
        float4 zv = A4[gi];
        zq4[gi] = cv;
        float dx = cv.x - zv.x, dy = cv.y - zv.y, dz = cv.z - zv.z, dw = cv.w - zv.w;
        acc += dx * dx + dy * dy + dz * dz + dw * dw;
    }
    #pragma unroll
    for (int d = 32; d; d >>= 1) acc += __shfl_xor(acc, d);
    __shared__ float ps[4];
    if ((threadIdx.x & 63) == 0) ps[threadIdx.x >> 6] = acc;
    __syncthreads();
    if (threadIdx.x == 0)
        partial[blockIdx.x] = ps[0] + ps[1] + ps[2] + ps[3];
}

// ---------------------------------------------------------------------------
// Kernel 4: reduce partials -> loss = sum / (B*N*D)
// ---------------------------------------------------------------------------
__global__ void vq_finish(const float* __restrict__ partial, float* __restrict__ out_loss) {
    float s = 0.0f;
    #pragma unroll
    for (int it = 0; it < GATHER_BLOCKS / 256; ++it)
        s += partial[threadIdx.x + it * 256];
    #pragma unroll
    for (int d = 32; d; d >>= 1) s += __shfl_xor(s, d);
    __shared__ float ps[4];
    if ((threadIdx.x & 63) == 0) ps[threadIdx.x >> 6] = s;
    __syncthreads();
    if (threadIdx.x == 0)
        *out_loss = (ps[0] + ps[1] + ps[2] + ps[3]) * (1.0f / 16777216.0f);
}

extern "C" void kernel_launch(void* const* d_in, const int* in_sizes, int n_in,
                              void* d_out, int out_size, void* d_ws, size_t ws_size,
                              hipStream_t stream) {
    const float* z_e = (const float*)d_in[0];
    const float* cb  = (const float*)d_in[1];

    float* out   = (float*)d_out;
    float* zq    = out;
    float* oidx  = out + (size_t)MTOT * KDIM;
    float* oloss = out + (size_t)MTOT * KDIM + MTOT;

    char* ws = (char*)d_ws;
    _Float16* cbh = (_Float16*)ws;                               // 512 KB
    _Float16* cbl = (_Float16*)(ws + 512 * 1024);                // 512 KB
    float* hn     = (float*)(ws + 1024 * 1024);                  // 4 KB
    int* iidx     = (int*)(ws + 1024 * 1024 + 4096);             // 256 KB
    float* part   = (float*)(ws + 1024 * 1024 + 4096 + 262144);  // 8 KB

    vq_prep<<<CBSZ / 4, 256, 0, stream>>>(cb, cbh, cbl, hn);
    vq_main<<<MTOT / 128, 256, 0, stream>>>(z_e, cbh, cbl, hn, oidx, iidx);
    vq_gather<<<GATHER_BLOCKS, 256, 0, stream>>>(z_e, cb, iidx, zq, part);
    vq_finish<<<1, 256, 0, stream>>>(part, oloss);
}